// Round 6
// baseline (869.100 us; speedup 1.0000x reference)
//
#include <hip/hip_runtime.h>
#include <hip/hip_bf16.h>

typedef __bf16 bf16x8 __attribute__((ext_vector_type(8)));
typedef float f32x4 __attribute__((ext_vector_type(4)));
typedef int i32x4 __attribute__((ext_vector_type(4)));

typedef __attribute__((address_space(1))) const void GVoid;
typedef __attribute__((address_space(3))) void LVoid;

// quant: x ~ (Xh + Xl/250)/16 ; Wqk ~ (Wh + Wl/250)/400 ; Relq ~ (Rh + Rl/250)/32 ; Wv ~ Wh/400
#define SX1 16.0f
#define SX1I 0.0625f
#define SX2 4000.0f
#define SW1 400.0f
#define SW1I 0.0025f
#define SW2 100000.0f
#define SR1 32.0f
#define SR1I 0.03125f
#define SR2 8000.0f
#define SC_QK 1.5625e-4f   /* 1/(16*400) */
#define SC_CP 1.953125e-3f /* 1/(16*32)  */
#define CORR 0.004f        /* 1/250 */

static __device__ __forceinline__ float b2f(unsigned short u) {
    union { float f; unsigned int i; } x; x.i = ((unsigned int)u) << 16; return x.f;
}
static __device__ __forceinline__ unsigned short f2b(float f) {
    union { float f; unsigned int u; } x; x.f = f;
    unsigned int r = x.u + 0x7FFFu + ((x.u >> 16) & 1u);
    return (unsigned short)(r >> 16);
}
static __device__ __forceinline__ int q8v(float v, float s) {
    int i = __float2int_rn(v * s);
    return (i > 127) ? 127 : (i < -127 ? -127 : i);
}

// ---------------- prep ----------------
// Wi8 layout: 1664 rows x 1024B [hi 512 | lo 512]
//   rows 0..1023  : Wq,Wk hi/lo
//   rows 1024..1079: Relq hi/lo ; 1080..1151: unused (never stored)
//   rows 1152..1663: Wv hi only
// biasA[1664]: bq | bk | relbias(56) | 0(72) | bv
__global__ __launch_bounds__(256) void k_prep(const float* __restrict__ Wq, const float* __restrict__ Wk,
                                              const float* __restrict__ Wv, const float* __restrict__ bq,
                                              const float* __restrict__ bk, const float* __restrict__ bv,
                                              const float* __restrict__ relw, char* __restrict__ Wi8,
                                              float* __restrict__ biasA) {
    int o = blockIdx.x;
    int tid = threadIdx.x;
    if (o < 1024) {
        const float* src = (o < 512) ? (Wq + (long)o * 512) : (Wk + (long)(o - 512) * 512);
        char* row = Wi8 + (long)o * 1024;
        for (int c = tid; c < 512; c += 256) {
            float w = src[c];
            int wh = q8v(w, SW1);
            float res = w - (float)wh * SW1I;
            int wl = q8v(res, SW2);
            row[c] = (char)wh;
            row[512 + c] = (char)wl;
        }
    } else if (o < 1536) {
        const float* src = Wv + (long)(o - 1024) * 512;
        char* row = Wi8 + (long)(1152 + (o - 1024)) * 1024;
        for (int c = tid; c < 512; c += 256) {
            float w = src[c];
            int wh = q8v(w, SW1);
            float res = w - (float)wh * SW1I;
            int wl = q8v(res, SW2);
            row[c] = (char)wh;
            row[512 + c] = (char)wl;
        }
    } else if (o < 1592) {
        int t = o - 1536, h = t / 14, i = t - h * 14;
        char* row = Wi8 + (long)(1024 + t) * 1024;
#pragma unroll
        for (int cc = 0; cc < 2; ++cc) {
            int c = tid + cc * 256;
            float acc = 0.f;
            for (int d = 0; d < 128; ++d)
                acc += relw[h * 1792 + d * 14 + i] * Wq[(long)(h * 128 + d) * 512 + c];
            int rh = q8v(acc, SR1);
            float res = acc - (float)rh * SR1I;
            int rl = q8v(res, SR2);
            row[c] = (char)rh;
            row[512 + c] = (char)rl;
        }
        if (tid == 0) {
            float acc = 0.f;
            for (int d = 0; d < 128; ++d) acc += relw[h * 1792 + d * 14 + i] * bq[h * 128 + d];
            biasA[1024 + t] = acc;
        }
    } else {
        for (int i = tid; i < 1664; i += 256) {
            if (i >= 1024 && i < 1080) continue;  // relbias written by Relq blocks
            biasA[i] = (i < 512) ? bq[i] : (i < 1024) ? bk[i - 512] : (i < 1152) ? 0.f : bv[i - 1152];
        }
        // zero the unused Wi8 rows 1080..1151 (deterministic, avoids reading poison)
        int* z = (int*)(Wi8 + (long)1080 * 1024);
        for (int idx = tid; idx < 72 * 256; idx += 256) z[idx] = 0;
    }
}

// ---------------- transpose: x[b][c][w] f32 -> Ai8[(b,w)][Xh(512)|Xl(512)] ----------------
__global__ __launch_bounds__(256) void k_transpose(const float* __restrict__ x,
                                                   char* __restrict__ Ai8, int b0) {
    __shared__ float xl[512 * 15];
    const float* xb = x + (long)(b0 + blockIdx.x) * 7168;
    const float4* xb4 = (const float4*)xb;
    int tid = threadIdx.x;
#pragma unroll
    for (int it = 0; it < 7; ++it) {
        int f = tid + it * 256;
        float4 v = xb4[f];
        float vals[4] = {v.x, v.y, v.z, v.w};
        int e = f * 4;
#pragma unroll
        for (int j = 0; j < 4; ++j) {
            int ee = e + j;
            int c = (ee * 9363) >> 17;
            int w = ee - c * 14;
            xl[c * 15 + w] = vals[j];
        }
    }
    __syncthreads();
    char* irow = Ai8 + (long)blockIdx.x * 14336;
#pragma unroll
    for (int it = 0; it < 7; ++it) {
        int p = tid + it * 256;        // 1792 quads: w = p>>7, c0 = (p&127)*4
        int w = p >> 7, c0 = (p & 127) * 4;
        unsigned int hp = 0, lp = 0;
#pragma unroll
        for (int j = 0; j < 4; ++j) {
            float v = xl[(c0 + j) * 15 + w];
            int xh = q8v(v, SX1);
            float res = v - (float)xh * SX1I;
            int xlo = q8v(res, SX2);
            hp |= ((unsigned int)(xh & 255)) << (8 * j);
            lp |= ((unsigned int)(xlo & 255)) << (8 * j);
        }
        *(unsigned int*)(irow + (long)w * 1024 + c0) = hp;
        *(unsigned int*)(irow + (long)w * 1024 + 512 + c0) = lp;
    }
}

// ---------------- GEMM-A: split-i8, 128x128 tile, BK=128 (128B rows, proven swizzle), N=1664 ----------------
// qk tiles (nt<9):  acc = AhBh + (AhBl + AlBh)/250 -> qkf f32 (n<1080)
// v  tiles (nt>=9): acc = AhBh + AlBh/250          -> vb bf16
__global__ __launch_bounds__(256) void k_gemmA(const char* __restrict__ Ai8,
                                               const char* __restrict__ Wi8,
                                               const float* __restrict__ biasA,
                                               float* __restrict__ qkf,
                                               unsigned short* __restrict__ vb, int Mtiles) {
    __shared__ __align__(16) char Ahs[128 * 128];
    __shared__ __align__(16) char Als[128 * 128];
    __shared__ __align__(16) char Bhs[128 * 128];
    __shared__ __align__(16) char Bls[128 * 128];
    int nwg = Mtiles * 13;
    int p = blockIdx.x;
    int xcd = p & 7, o8 = p >> 3;
    int q8_ = nwg >> 3, r8 = nwg & 7;
    int t = (xcd < r8 ? xcd * (q8_ + 1) : r8 * (q8_ + 1) + (xcd - r8) * q8_) + o8;
    int mt = t / 13, nt = t - mt * 13;
    long m0 = (long)mt * 128;
    int n0 = nt * 128;
    bool isv = (nt >= 9);
    int tid = threadIdx.x, lane = tid & 63, wv = tid >> 6;
    int wr = wv >> 1, wc = wv & 1;
    int rrow = lane >> 3;   // 8 rows per 1KB chunk
    int u = lane & 7;       // 8 16B units per 128B row

    i32x4 accM[4][4], accC[4][4];
#pragma unroll
    for (int i = 0; i < 4; ++i)
#pragma unroll
        for (int j = 0; j < 4; ++j) { accM[i][j] = (i32x4){0, 0, 0, 0}; accC[i][j] = (i32x4){0, 0, 0, 0}; }

    for (int kt = 0; kt < 4; ++kt) {
        int kof = kt * 128;
#pragma unroll
        for (int ti = 0; ti < 4; ++ti) {
            int chunk = wv * 4 + ti;
            int row = chunk * 8 + rrow;
            int gu = ((u ^ (row & 7)) << 4);
            const char* sa = Ai8 + ((m0 + row) << 10) + kof + gu;
            const char* sb = Wi8 + ((long)(n0 + row) << 10) + kof + gu;
            __builtin_amdgcn_global_load_lds((GVoid*)sa, (LVoid*)(Ahs + chunk * 1024), 16, 0, 0);
            __builtin_amdgcn_global_load_lds((GVoid*)(sa + 512), (LVoid*)(Als + chunk * 1024), 16, 0, 0);
            __builtin_amdgcn_global_load_lds((GVoid*)sb, (LVoid*)(Bhs + chunk * 1024), 16, 0, 0);
            if (!isv)
                __builtin_amdgcn_global_load_lds((GVoid*)(sb + 512), (LVoid*)(Bls + chunk * 1024), 16, 0, 0);
        }
        asm volatile("s_waitcnt vmcnt(0)" ::: "memory");
        __syncthreads();
#pragma unroll
        for (int kk = 0; kk < 2; ++kk) {
            i32x4 ah[4], al[4], bh[4], bl[4];
            int kb = kk * 64 + ((lane >> 4) << 4);
#pragma unroll
            for (int mf = 0; mf < 4; ++mf) {
                int row = wr * 64 + mf * 16 + (lane & 15);
                int off = row * 128 + (kb ^ ((row & 7) << 4));
                ah[mf] = *(const i32x4*)(Ahs + off);
                al[mf] = *(const i32x4*)(Als + off);
            }
#pragma unroll
            for (int nf = 0; nf < 4; ++nf) {
                int row = wc * 64 + nf * 16 + (lane & 15);
                int off = row * 128 + (kb ^ ((row & 7) << 4));
                bh[nf] = *(const i32x4*)(Bhs + off);
                bl[nf] = *(const i32x4*)(Bls + off);
            }
#pragma unroll
            for (int mf = 0; mf < 4; ++mf)
#pragma unroll
                for (int nf = 0; nf < 4; ++nf) {
                    accM[mf][nf] = __builtin_amdgcn_mfma_i32_16x16x64_i8(ah[mf], bh[nf], accM[mf][nf], 0, 0, 0);
                    if (!isv)
                        accC[mf][nf] = __builtin_amdgcn_mfma_i32_16x16x64_i8(ah[mf], bl[nf], accC[mf][nf], 0, 0, 0);
                    accC[mf][nf] = __builtin_amdgcn_mfma_i32_16x16x64_i8(al[mf], bh[nf], accC[mf][nf], 0, 0, 0);
                }
        }
        __syncthreads();
    }
#pragma unroll
    for (int nf = 0; nf < 4; ++nf) {
        int n = n0 + wc * 64 + nf * 16 + (lane & 15);
        float scale = (n < 1024) ? SC_QK : (n < 1152 ? SC_CP : SC_QK);
        float bb = biasA[n];
#pragma unroll
        for (int mf = 0; mf < 4; ++mf) {
            long mg = m0 + wr * 64 + mf * 16 + ((lane >> 4) << 2);
#pragma unroll
            for (int r = 0; r < 4; ++r) {
                float val = ((float)accM[mf][nf][r] + CORR * (float)accC[mf][nf][r]) * scale + bb;
                if (n < 1080) qkf[(mg + r) * 1152 + n] = val;
                else if (n >= 1152) vb[(mg + r) * 512 + (n - 1152)] = f2b(val);
            }
        }
    }
}

// ---------------- attention: one b per 512-thread block (R5 proven) ----------------
// qkf row (b,w): [0..511]=q, [512..1023]=k, [1024..1079]=cp cols (h*14+i)
__global__ __launch_bounds__(512) void k_attn(const float* __restrict__ qkf,
                                              const unsigned short* __restrict__ vb,
                                              float* __restrict__ out, int b0) {
    __shared__ float qs[14 * 512];   // row w: 128 16B-units, unit idx ^ (w&7)
    __shared__ float ks[14 * 512];
    __shared__ float cps[56 * 16];   // [h*14+i][j]
    __shared__ float sl[56 * 16];
    __shared__ unsigned short vs[14 * 512];
    int tid = threadIdx.x;
    long mb = (long)blockIdx.x * 14;
    const float4* qk4 = (const float4*)qkf;  // 288 units per row
#pragma unroll
    for (int it = 0; it < 7; ++it) {
        int idx = tid + it * 512;
        int w = idx >> 8, c4 = idx & 255;
        float4 v = qk4[(mb + w) * 288 + c4];
        if (c4 < 128) *(float4*)&qs[w * 512 + ((c4 ^ (w & 7)) << 2)] = v;
        else {
            int uu = c4 - 128;
            *(float4*)&ks[w * 512 + ((uu ^ (w & 7)) << 2)] = v;
        }
    }
#pragma unroll
    for (int it = 0; it < 2; ++it) {
        int idx = tid + it * 512;
        if (idx < 784) {
            int w = idx / 56, tt = idx - w * 56;
            cps[tt * 16 + w] = qkf[(mb + w) * 1152 + 1024 + tt];
        }
    }
#pragma unroll
    for (int it = 0; it < 2; ++it) {
        int idx = tid + it * 512;
        if (idx < 896) {
            int w = idx >> 6, uu = idx & 63;
            *(uint4*)&vs[w * 512 + uu * 8] = *(const uint4*)&vb[(mb + w) * 512 + uu * 8];
        }
    }
    __syncthreads();
    if (tid < 196) {
        int h = tid / 49, r = tid - h * 49;
        int i0 = (r / 7) * 2, j0 = (r - (r / 7) * 7) * 2;
        float a00 = 0.f, a01 = 0.f, a10 = 0.f, a11 = 0.f;
#pragma unroll
        for (int d4 = 0; d4 < 32; ++d4) {
            int uu = h * 32 + d4;
            float4 qa = *(const float4*)&qs[i0 * 512 + ((uu ^ (i0 & 7)) << 2)];
            float4 qb = *(const float4*)&qs[(i0 + 1) * 512 + ((uu ^ ((i0 + 1) & 7)) << 2)];
            float4 ka = *(const float4*)&ks[j0 * 512 + ((uu ^ (j0 & 7)) << 2)];
            float4 kb = *(const float4*)&ks[(j0 + 1) * 512 + ((uu ^ ((j0 + 1) & 7)) << 2)];
            a00 += qa.x * ka.x + qa.y * ka.y + qa.z * ka.z + qa.w * ka.w;
            a01 += qa.x * kb.x + qa.y * kb.y + qa.z * kb.z + qa.w * kb.w;
            a10 += qb.x * ka.x + qb.y * ka.y + qb.z * ka.z + qb.w * ka.w;
            a11 += qb.x * kb.x + qb.y * kb.y + qb.z * kb.z + qb.w * kb.w;
        }
        int base = (h * 14 + i0) * 16 + j0;
        sl[base] = a00 + cps[base];
        sl[base + 1] = a01 + cps[base + 1];
        sl[base + 16] = a10 + cps[base + 16];
        sl[base + 17] = a11 + cps[base + 17];
    }
    __syncthreads();
    if (tid < 56) {
        float* row = &sl[tid * 16];
        float m = row[0];
#pragma unroll
        for (int j = 1; j < 14; ++j) m = fmaxf(m, row[j]);
        float ex[14]; float sum = 0.f;
#pragma unroll
        for (int j = 0; j < 14; ++j) { ex[j] = __expf(row[j] - m); sum += ex[j]; }
        float inv = 1.f / sum;
#pragma unroll
        for (int j = 0; j < 14; ++j) row[j] = ex[j] * inv;
    }
    __syncthreads();
    int c = tid, h = c >> 7;
    float vr[14];
#pragma unroll
    for (int j = 0; j < 14; ++j) vr[j] = b2f(vs[j * 512 + c]);
    float* orow = out + (((long)(b0 + blockIdx.x) * 512 + c) * 14);
    float ob[14];
#pragma unroll
    for (int i = 0; i < 14; ++i) {
        const float* ar = &sl[(h * 14 + i) * 16];
        float a = 0.f;
#pragma unroll
        for (int j = 0; j < 14; ++j) a += vr[j] * ar[j];
        ob[i] = a;
    }
#pragma unroll
    for (int t2 = 0; t2 < 7; ++t2)
        *(float2*)(orow + t2 * 2) = make_float2(ob[2 * t2], ob[2 * t2 + 1]);
}

extern "C" void kernel_launch(void* const* d_in, const int* in_sizes, int n_in,
                              void* d_out, int out_size, void* d_ws, size_t ws_size,
                              hipStream_t stream) {
    const float* x    = (const float*)d_in[0];
    const float* Wq   = (const float*)d_in[1];
    const float* bq   = (const float*)d_in[2];
    const float* Wk   = (const float*)d_in[3];
    const float* bk   = (const float*)d_in[4];
    const float* Wv   = (const float*)d_in[5];
    const float* bv   = (const float*)d_in[6];
    const float* relw = (const float*)d_in[7];
    float* out = (float*)d_out;
    char* ws = (char*)d_ws;

    char*  Wi8   = ws;                       // 1664*1024 = 1703936
    float* biasA = (float*)(ws + 1703936);   // 1664*4 = 6656
    const long WS_DATA = 1712128;            // aligned

    // per-b: Ai8 14336 + qkf 64512 + vb 14336 = 93184 B
    long avail = (long)ws_size - WS_DATA;
    long nbmax = avail / 93184;
    long NBc = (nbmax / 128) * 128;
    if (NBc > 8192) NBc = 8192;
    if (NBc < 128) NBc = 128;

    char*           Ai8 = ws + WS_DATA;
    float*          qkf = (float*)(Ai8 + NBc * 14336);
    unsigned short* vbw = (unsigned short*)(qkf + NBc * 16128);

    k_prep<<<1593, 256, 0, stream>>>(Wq, Wk, Wv, bq, bk, bv, relw, Wi8, biasA);

    for (int b0 = 0; b0 < 8192; b0 += (int)NBc) {
        int nb = 8192 - b0; if (nb > NBc) nb = (int)NBc;
        int Mtiles = (nb * 14) / 128;
        k_transpose<<<nb, 256, 0, stream>>>(x, Ai8, b0);
        k_gemmA<<<Mtiles * 13, 256, 0, stream>>>(Ai8, Wi8, biasA, qkf, vbw, Mtiles);
        k_attn<<<nb, 512, 0, stream>>>(qkf, vbw, out, b0);
    }
}

// Round 7
// 731.688 us; speedup vs baseline: 1.1878x; 1.1878x over previous
//
#include <hip/hip_runtime.h>
#include <hip/hip_bf16.h>

typedef __bf16 bf16x8 __attribute__((ext_vector_type(8)));
typedef float f32x4 __attribute__((ext_vector_type(4)));
typedef int i32x4 __attribute__((ext_vector_type(4)));

typedef __attribute__((address_space(1))) const void GVoid;
typedef __attribute__((address_space(3))) void LVoid;

// quant: x ~ (Xh + Xl/250)/16 ; W ~ (Wh + Wl/250)/400 ; Relq ~ (Rh + Rl/250)/32
#define SX1 16.0f
#define SX1I 0.0625f
#define SX2 4000.0f
#define SW1 400.0f
#define SW1I 0.0025f
#define SW2 100000.0f
#define SR1 32.0f
#define SR1I 0.03125f
#define SR2 8000.0f
#define SC_QK 1.5625e-4f   /* 1/(16*400) */
#define SC_CP 1.953125e-3f /* 1/(16*32)  */
#define CORR 0.004f        /* 1/250 */

static __device__ __forceinline__ float b2f(unsigned short u) {
    union { float f; unsigned int i; } x; x.i = ((unsigned int)u) << 16; return x.f;
}
static __device__ __forceinline__ unsigned short f2b(float f) {
    union { float f; unsigned int u; } x; x.f = f;
    unsigned int r = x.u + 0x7FFFu + ((x.u >> 16) & 1u);
    return (unsigned short)(r >> 16);
}
static __device__ __forceinline__ int q8v(float v, float s) {
    int i = __float2int_rn(v * s);
    return (i > 127) ? 127 : (i < -127 ? -127 : i);
}

// ---------------- prep ----------------
// Wi8 layout: 1664 rows x 1024B [hi 512 | lo 512]
//   rows 0..1023   : Wq,Wk hi/lo
//   rows 1024..1079: Relq hi/lo ; 1080..1151: zeroed
//   rows 1152..1663: Wv hi/lo
// biasA[1664]: bq | bk | relbias(56) | 0(72) | bv
__global__ __launch_bounds__(256) void k_prep(const float* __restrict__ Wq, const float* __restrict__ Wk,
                                              const float* __restrict__ Wv, const float* __restrict__ bq,
                                              const float* __restrict__ bk, const float* __restrict__ bv,
                                              const float* __restrict__ relw, char* __restrict__ Wi8,
                                              float* __restrict__ biasA) {
    int o = blockIdx.x;
    int tid = threadIdx.x;
    if (o < 1024) {
        const float* src = (o < 512) ? (Wq + (long)o * 512) : (Wk + (long)(o - 512) * 512);
        char* row = Wi8 + (long)o * 1024;
        for (int c = tid; c < 512; c += 256) {
            float w = src[c];
            int wh = q8v(w, SW1);
            float res = w - (float)wh * SW1I;
            int wl = q8v(res, SW2);
            row[c] = (char)wh;
            row[512 + c] = (char)wl;
        }
    } else if (o < 1536) {
        const float* src = Wv + (long)(o - 1024) * 512;
        char* row = Wi8 + (long)(1152 + (o - 1024)) * 1024;
        for (int c = tid; c < 512; c += 256) {
            float w = src[c];
            int wh = q8v(w, SW1);
            float res = w - (float)wh * SW1I;
            int wl = q8v(res, SW2);
            row[c] = (char)wh;
            row[512 + c] = (char)wl;
        }
    } else if (o < 1592) {
        int t = o - 1536, h = t / 14, i = t - h * 14;
        char* row = Wi8 + (long)(1024 + t) * 1024;
#pragma unroll
        for (int cc = 0; cc < 2; ++cc) {
            int c = tid + cc * 256;
            float acc = 0.f;
            for (int d = 0; d < 128; ++d)
                acc += relw[h * 1792 + d * 14 + i] * Wq[(long)(h * 128 + d) * 512 + c];
            int rh = q8v(acc, SR1);
            float res = acc - (float)rh * SR1I;
            int rl = q8v(res, SR2);
            row[c] = (char)rh;
            row[512 + c] = (char)rl;
        }
        if (tid == 0) {
            float acc = 0.f;
            for (int d = 0; d < 128; ++d) acc += relw[h * 1792 + d * 14 + i] * bq[h * 128 + d];
            biasA[1024 + t] = acc;
        }
    } else {
        for (int i = tid; i < 1664; i += 256) {
            if (i >= 1024 && i < 1080) continue;  // relbias written by Relq blocks
            biasA[i] = (i < 512) ? bq[i] : (i < 1024) ? bk[i - 512] : (i < 1152) ? 0.f : bv[i - 1152];
        }
        int* z = (int*)(Wi8 + (long)1080 * 1024);
        for (int idx = tid; idx < 72 * 256; idx += 256) z[idx] = 0;
    }
}

// ---------------- transpose: x[b][c][w] f32 -> Ai8[(b,w)][Xh(512)|Xl(512)] ----------------
__global__ __launch_bounds__(256) void k_transpose(const float* __restrict__ x,
                                                   char* __restrict__ Ai8, int b0) {
    __shared__ float xl[512 * 15];
    const float* xb = x + (long)(b0 + blockIdx.x) * 7168;
    const float4* xb4 = (const float4*)xb;
    int tid = threadIdx.x;
#pragma unroll
    for (int it = 0; it < 7; ++it) {
        int f = tid + it * 256;
        float4 v = xb4[f];
        float vals[4] = {v.x, v.y, v.z, v.w};
        int e = f * 4;
#pragma unroll
        for (int j = 0; j < 4; ++j) {
            int ee = e + j;
            int c = (ee * 9363) >> 17;
            int w = ee - c * 14;
            xl[c * 15 + w] = vals[j];
        }
    }
    __syncthreads();
    char* irow = Ai8 + (long)blockIdx.x * 14336;
#pragma unroll
    for (int it = 0; it < 7; ++it) {
        int p = tid + it * 256;        // 1792 quads: w = p>>7, c0 = (p&127)*4
        int w = p >> 7, c0 = (p & 127) * 4;
        unsigned int hp = 0, lp = 0;
#pragma unroll
        for (int j = 0; j < 4; ++j) {
            float v = xl[(c0 + j) * 15 + w];
            int xh = q8v(v, SX1);
            float res = v - (float)xh * SX1I;
            int xlo = q8v(res, SX2);
            hp |= ((unsigned int)(xh & 255)) << (8 * j);
            lp |= ((unsigned int)(xlo & 255)) << (8 * j);
        }
        *(unsigned int*)(irow + (long)w * 1024 + c0) = hp;
        *(unsigned int*)(irow + (long)w * 1024 + 512 + c0) = lp;
    }
}

// ---------------- GEMM-A: split-i8, 128x128 tile, BK=128, N=1664, uniform K-loop ----------------
// acc = AhBh + (AhBl + AlBh)/250 ; qk tiles -> qkf f32 ; v tiles -> vb bf16
__global__ __launch_bounds__(256, 2) void k_gemmA(const char* __restrict__ Ai8,
                                                  const char* __restrict__ Wi8,
                                                  const float* __restrict__ biasA,
                                                  float* __restrict__ qkf,
                                                  unsigned short* __restrict__ vb, int Mtiles) {
    __shared__ __align__(16) char Ahs[128 * 128];
    __shared__ __align__(16) char Als[128 * 128];
    __shared__ __align__(16) char Bhs[128 * 128];
    __shared__ __align__(16) char Bls[128 * 128];
    int nwg = Mtiles * 13;
    int p = blockIdx.x;
    int xcd = p & 7, o8 = p >> 3;
    int q8_ = nwg >> 3, r8 = nwg & 7;
    int t = (xcd < r8 ? xcd * (q8_ + 1) : r8 * (q8_ + 1) + (xcd - r8) * q8_) + o8;
    int mt = t / 13, nt = t - mt * 13;
    long m0 = (long)mt * 128;
    int n0 = nt * 128;
    int tid = threadIdx.x, lane = tid & 63, wv = tid >> 6;
    int wr = wv >> 1, wc = wv & 1;
    int rrow = lane >> 3;   // 8 rows per 1KB chunk
    int u = lane & 7;       // 8 16B units per 128B row

    i32x4 accM[4][4], accC[4][4];
#pragma unroll
    for (int i = 0; i < 4; ++i)
#pragma unroll
        for (int j = 0; j < 4; ++j) { accM[i][j] = (i32x4){0, 0, 0, 0}; accC[i][j] = (i32x4){0, 0, 0, 0}; }

    for (int kt = 0; kt < 4; ++kt) {
        int kof = kt * 128;
#pragma unroll
        for (int ti = 0; ti < 4; ++ti) {
            int chunk = wv * 4 + ti;
            int row = chunk * 8 + rrow;
            int gu = ((u ^ (row & 7)) << 4);
            const char* sa = Ai8 + ((m0 + row) << 10) + kof + gu;
            const char* sb = Wi8 + ((long)(n0 + row) << 10) + kof + gu;
            __builtin_amdgcn_global_load_lds((GVoid*)sa, (LVoid*)(Ahs + chunk * 1024), 16, 0, 0);
            __builtin_amdgcn_global_load_lds((GVoid*)(sa + 512), (LVoid*)(Als + chunk * 1024), 16, 0, 0);
            __builtin_amdgcn_global_load_lds((GVoid*)sb, (LVoid*)(Bhs + chunk * 1024), 16, 0, 0);
            __builtin_amdgcn_global_load_lds((GVoid*)(sb + 512), (LVoid*)(Bls + chunk * 1024), 16, 0, 0);
        }
        asm volatile("s_waitcnt vmcnt(0)" ::: "memory");
        __syncthreads();
#pragma unroll
        for (int kk = 0; kk < 2; ++kk) {
            i32x4 ah[4], al[4], bh[4], bl[4];
            int kb = kk * 64 + ((lane >> 4) << 4);
#pragma unroll
            for (int mf = 0; mf < 4; ++mf) {
                int row = wr * 64 + mf * 16 + (lane & 15);
                int off = row * 128 + (kb ^ ((row & 7) << 4));
                ah[mf] = *(const i32x4*)(Ahs + off);
                al[mf] = *(const i32x4*)(Als + off);
            }
#pragma unroll
            for (int nf = 0; nf < 4; ++nf) {
                int row = wc * 64 + nf * 16 + (lane & 15);
                int off = row * 128 + (kb ^ ((row & 7) << 4));
                bh[nf] = *(const i32x4*)(Bhs + off);
                bl[nf] = *(const i32x4*)(Bls + off);
            }
#pragma unroll
            for (int mf = 0; mf < 4; ++mf)
#pragma unroll
                for (int nf = 0; nf < 4; ++nf) {
                    accM[mf][nf] = __builtin_amdgcn_mfma_i32_16x16x64_i8(ah[mf], bh[nf], accM[mf][nf], 0, 0, 0);
                    accC[mf][nf] = __builtin_amdgcn_mfma_i32_16x16x64_i8(ah[mf], bl[nf], accC[mf][nf], 0, 0, 0);
                    accC[mf][nf] = __builtin_amdgcn_mfma_i32_16x16x64_i8(al[mf], bh[nf], accC[mf][nf], 0, 0, 0);
                }
        }
        __syncthreads();
    }
#pragma unroll
    for (int nf = 0; nf < 4; ++nf) {
        int n = n0 + wc * 64 + nf * 16 + (lane & 15);
        float scale = (n < 1024) ? SC_QK : (n < 1152 ? SC_CP : SC_QK);
        float bb = biasA[n];
#pragma unroll
        for (int mf = 0; mf < 4; ++mf) {
            long mg = m0 + wr * 64 + mf * 16 + ((lane >> 4) << 2);
#pragma unroll
            for (int r = 0; r < 4; ++r) {
                float val = ((float)accM[mf][nf][r] + CORR * (float)accC[mf][nf][r]) * scale + bb;
                if (n < 1080) qkf[(mg + r) * 1152 + n] = val;
                else if (n >= 1152) vb[(mg + r) * 512 + (n - 1152)] = f2b(val);
            }
        }
    }
}

// ---------------- attention: one b per 512-thread block (proven) ----------------
// qkf row (b,w): [0..511]=q, [512..1023]=k, [1024..1079]=cp cols (h*14+i)
__global__ __launch_bounds__(512) void k_attn(const float* __restrict__ qkf,
                                              const unsigned short* __restrict__ vb,
                                              float* __restrict__ out, int b0) {
    __shared__ float qs[14 * 512];   // row w: 128 16B-units, unit idx ^ (w&7)
    __shared__ float ks[14 * 512];
    __shared__ float cps[56 * 16];   // [h*14+i][j]
    __shared__ float sl[56 * 16];
    __shared__ unsigned short vs[14 * 512];
    int tid = threadIdx.x;
    long mb = (long)blockIdx.x * 14;
    const float4* qk4 = (const float4*)qkf;  // 288 units per row
#pragma unroll
    for (int it = 0; it < 7; ++it) {
        int idx = tid + it * 512;
        int w = idx >> 8, c4 = idx & 255;
        float4 v = qk4[(mb + w) * 288 + c4];
        if (c4 < 128) *(float4*)&qs[w * 512 + ((c4 ^ (w & 7)) << 2)] = v;
        else {
            int uu = c4 - 128;
            *(float4*)&ks[w * 512 + ((uu ^ (w & 7)) << 2)] = v;
        }
    }
#pragma unroll
    for (int it = 0; it < 2; ++it) {
        int idx = tid + it * 512;
        if (idx < 784) {
            int w = idx / 56, tt = idx - w * 56;
            cps[tt * 16 + w] = qkf[(mb + w) * 1152 + 1024 + tt];
        }
    }
#pragma unroll
    for (int it = 0; it < 2; ++it) {
        int idx = tid + it * 512;
        if (idx < 896) {
            int w = idx >> 6, uu = idx & 63;
            *(uint4*)&vs[w * 512 + uu * 8] = *(const uint4*)&vb[(mb + w) * 512 + uu * 8];
        }
    }
    __syncthreads();
    if (tid < 196) {
        int h = tid / 49, r = tid - h * 49;
        int i0 = (r / 7) * 2, j0 = (r - (r / 7) * 7) * 2;
        float a00 = 0.f, a01 = 0.f, a10 = 0.f, a11 = 0.f;
#pragma unroll
        for (int d4 = 0; d4 < 32; ++d4) {
            int uu = h * 32 + d4;
            float4 qa = *(const float4*)&qs[i0 * 512 + ((uu ^ (i0 & 7)) << 2)];
            float4 qb = *(const float4*)&qs[(i0 + 1) * 512 + ((uu ^ ((i0 + 1) & 7)) << 2)];
            float4 ka = *(const float4*)&ks[j0 * 512 + ((uu ^ (j0 & 7)) << 2)];
            float4 kb = *(const float4*)&ks[(j0 + 1) * 512 + ((uu ^ ((j0 + 1) & 7)) << 2)];
            a00 += qa.x * ka.x + qa.y * ka.y + qa.z * ka.z + qa.w * ka.w;
            a01 += qa.x * kb.x + qa.y * kb.y + qa.z * kb.z + qa.w * kb.w;
            a10 += qb.x * ka.x + qb.y * ka.y + qb.z * ka.z + qb.w * ka.w;
            a11 += qb.x * kb.x + qb.y * kb.y + qb.z * kb.z + qb.w * kb.w;
        }
        int base = (h * 14 + i0) * 16 + j0;
        sl[base] = a00 + cps[base];
        sl[base + 1] = a01 + cps[base + 1];
        sl[base + 16] = a10 + cps[base + 16];
        sl[base + 17] = a11 + cps[base + 17];
    }
    __syncthreads();
    if (tid < 56) {
        float* row = &sl[tid * 16];
        float m = row[0];
#pragma unroll
        for (int j = 1; j < 14; ++j) m = fmaxf(m, row[j]);
        float ex[14]; float sum = 0.f;
#pragma unroll
        for (int j = 0; j < 14; ++j) { ex[j] = __expf(row[j] - m); sum += ex[j]; }
        float inv = 1.f / sum;
#pragma unroll
        for (int j = 0; j < 14; ++j) row[j] = ex[j] * inv;
    }
    __syncthreads();
    int c = tid, h = c >> 7;
    float vr[14];
#pragma unroll
    for (int j = 0; j < 14; ++j) vr[j] = b2f(vs[j * 512 + c]);
    float* orow = out + (((long)(b0 + blockIdx.x) * 512 + c) * 14);
    float ob[14];
#pragma unroll
    for (int i = 0; i < 14; ++i) {
        const float* ar = &sl[(h * 14 + i) * 16];
        float a = 0.f;
#pragma unroll
        for (int j = 0; j < 14; ++j) a += vr[j] * ar[j];
        ob[i] = a;
    }
#pragma unroll
    for (int t2 = 0; t2 < 7; ++t2)
        *(float2*)(orow + t2 * 2) = make_float2(ob[2 * t2], ob[2 * t2 + 1]);
}

extern "C" void kernel_launch(void* const* d_in, const int* in_sizes, int n_in,
                              void* d_out, int out_size, void* d_ws, size_t ws_size,
                              hipStream_t stream) {
    const float* x    = (const float*)d_in[0];
    const float* Wq   = (const float*)d_in[1];
    const float* bq   = (const float*)d_in[2];
    const float* Wk   = (const float*)d_in[3];
    const float* bk   = (const float*)d_in[4];
    const float* Wv   = (const float*)d_in[5];
    const float* bv   = (const float*)d_in[6];
    const float* relw = (const float*)d_in[7];
    float* out = (float*)d_out;
    char* ws = (char*)d_ws;

    char*  Wi8   = ws;                       // 1664*1024 = 1703936
    float* biasA = (float*)(ws + 1703936);   // 1664*4 = 6656
    const long WS_DATA = 1712128;

    // per-b: Ai8 14336 + qkf 64512 + vb 14336 = 93184 B
    long avail = (long)ws_size - WS_DATA;
    long nbmax = avail / 93184;
    long NBc = (nbmax / 128) * 128;
    if (NBc > 8192) NBc = 8192;
    if (NBc < 128) NBc = 128;

    char*           Ai8 = ws + WS_DATA;
    float*          qkf = (float*)(Ai8 + NBc * 14336);
    unsigned short* vbw = (unsigned short*)(qkf + NBc * 16128);

    k_prep<<<1593, 256, 0, stream>>>(Wq, Wk, Wv, bq, bk, bv, relw, Wi8, biasA);

    for (int b0 = 0; b0 < 8192; b0 += (int)NBc) {
        int nb = 8192 - b0; if (nb > NBc) nb = (int)NBc;
        int Mtiles = (nb * 14) / 128;
        k_transpose<<<nb, 256, 0, stream>>>(x, Ai8, b0);
        k_gemmA<<<Mtiles * 13, 256, 0, stream>>>(Ai8, Wi8, biasA, qkf, vbw, Mtiles);
        k_attn<<<nb, 512, 0, stream>>>(qkf, vbw, out, b0);
    }
}

// Round 8
// 728.672 us; speedup vs baseline: 1.1927x; 1.0041x over previous
//
#include <hip/hip_runtime.h>
#include <hip/hip_bf16.h>

typedef __bf16 bf16x8 __attribute__((ext_vector_type(8)));
typedef float f32x4 __attribute__((ext_vector_type(4)));
typedef int i32x4 __attribute__((ext_vector_type(4)));

typedef __attribute__((address_space(1))) const void GVoid;
typedef __attribute__((address_space(3))) void LVoid;

// quant: x ~ (Xh + Xl/250)/16 ; W ~ (Wh + Wl/250)/400 ; Relq ~ (Rh + Rl/250)/32
#define SX1 16.0f
#define SX1I 0.0625f
#define SX2 4000.0f
#define SW1 400.0f
#define SW1I 0.0025f
#define SW2 100000.0f
#define SR1 32.0f
#define SR1I 0.03125f
#define SR2 8000.0f
#define SC_QK 1.5625e-4f   /* 1/(16*400) */
#define SC_CP 1.953125e-3f /* 1/(16*32)  */
#define CORR 0.004f        /* 1/250 */

static __device__ __forceinline__ float b2f(unsigned short u) {
    union { float f; unsigned int i; } x; x.i = ((unsigned int)u) << 16; return x.f;
}
static __device__ __forceinline__ unsigned short f2b(float f) {
    union { float f; unsigned int u; } x; x.f = f;
    unsigned int r = x.u + 0x7FFFu + ((x.u >> 16) & 1u);
    return (unsigned short)(r >> 16);
}
static __device__ __forceinline__ int q8v(float v, float s) {
    int i = __float2int_rn(v * s);
    return (i > 127) ? 127 : (i < -127 ? -127 : i);
}

// ---------------- prep ----------------
// Wi8 layout: 1664 rows x 1024B [hi 512 | lo 512]
//   rows 0..1023   : Wq,Wk hi/lo
//   rows 1024..1079: Relq hi/lo ; 1080..1151: zeroed
//   rows 1152..1663: Wv hi/lo
// biasA[1664]: bq | bk | relbias(56) | 0(72) | bv
__global__ __launch_bounds__(256) void k_prep(const float* __restrict__ Wq, const float* __restrict__ Wk,
                                              const float* __restrict__ Wv, const float* __restrict__ bq,
                                              const float* __restrict__ bk, const float* __restrict__ bv,
                                              const float* __restrict__ relw, char* __restrict__ Wi8,
                                              float* __restrict__ biasA) {
    int o = blockIdx.x;
    int tid = threadIdx.x;
    if (o < 1024) {
        const float* src = (o < 512) ? (Wq + (long)o * 512) : (Wk + (long)(o - 512) * 512);
        char* row = Wi8 + (long)o * 1024;
        for (int c = tid; c < 512; c += 256) {
            float w = src[c];
            int wh = q8v(w, SW1);
            float res = w - (float)wh * SW1I;
            int wl = q8v(res, SW2);
            row[c] = (char)wh;
            row[512 + c] = (char)wl;
        }
    } else if (o < 1536) {
        const float* src = Wv + (long)(o - 1024) * 512;
        char* row = Wi8 + (long)(1152 + (o - 1024)) * 1024;
        for (int c = tid; c < 512; c += 256) {
            float w = src[c];
            int wh = q8v(w, SW1);
            float res = w - (float)wh * SW1I;
            int wl = q8v(res, SW2);
            row[c] = (char)wh;
            row[512 + c] = (char)wl;
        }
    } else if (o < 1592) {
        int t = o - 1536, h = t / 14, i = t - h * 14;
        char* row = Wi8 + (long)(1024 + t) * 1024;
#pragma unroll
        for (int cc = 0; cc < 2; ++cc) {
            int c = tid + cc * 256;
            float acc = 0.f;
            for (int d = 0; d < 128; ++d)
                acc += relw[h * 1792 + d * 14 + i] * Wq[(long)(h * 128 + d) * 512 + c];
            int rh = q8v(acc, SR1);
            float res = acc - (float)rh * SR1I;
            int rl = q8v(res, SR2);
            row[c] = (char)rh;
            row[512 + c] = (char)rl;
        }
        if (tid == 0) {
            float acc = 0.f;
            for (int d = 0; d < 128; ++d) acc += relw[h * 1792 + d * 14 + i] * bq[h * 128 + d];
            biasA[1024 + t] = acc;
        }
    } else {
        for (int i = tid; i < 1664; i += 256) {
            if (i >= 1024 && i < 1080) continue;  // relbias written by Relq blocks
            biasA[i] = (i < 512) ? bq[i] : (i < 1024) ? bk[i - 512] : (i < 1152) ? 0.f : bv[i - 1152];
        }
        int* z = (int*)(Wi8 + (long)1080 * 1024);
        for (int idx = tid; idx < 72 * 256; idx += 256) z[idx] = 0;
    }
}

// ---------------- transpose: x[b][c][w] f32 -> Ai8[(b,w)][Xh(512)|Xl(512)] ----------------
__global__ __launch_bounds__(256) void k_transpose(const float* __restrict__ x,
                                                   char* __restrict__ Ai8, int b0) {
    __shared__ float xl[512 * 15];
    const float* xb = x + (long)(b0 + blockIdx.x) * 7168;
    const float4* xb4 = (const float4*)xb;
    int tid = threadIdx.x;
#pragma unroll
    for (int it = 0; it < 7; ++it) {
        int f = tid + it * 256;
        float4 v = xb4[f];
        float vals[4] = {v.x, v.y, v.z, v.w};
        int e = f * 4;
#pragma unroll
        for (int j = 0; j < 4; ++j) {
            int ee = e + j;
            int c = (ee * 9363) >> 17;
            int w = ee - c * 14;
            xl[c * 15 + w] = vals[j];
        }
    }
    __syncthreads();
    char* irow = Ai8 + (long)blockIdx.x * 14336;
#pragma unroll
    for (int it = 0; it < 7; ++it) {
        int p = tid + it * 256;        // 1792 quads: w = p>>7, c0 = (p&127)*4
        int w = p >> 7, c0 = (p & 127) * 4;
        unsigned int hp = 0, lp = 0;
#pragma unroll
        for (int j = 0; j < 4; ++j) {
            float v = xl[(c0 + j) * 15 + w];
            int xh = q8v(v, SX1);
            float res = v - (float)xh * SX1I;
            int xlo = q8v(res, SX2);
            hp |= ((unsigned int)(xh & 255)) << (8 * j);
            lp |= ((unsigned int)(xlo & 255)) << (8 * j);
        }
        *(unsigned int*)(irow + (long)w * 1024 + c0) = hp;
        *(unsigned int*)(irow + (long)w * 1024 + 512 + c0) = lp;
    }
}

// ---------------- GEMM-A: split-i8, 128x128 tile, BK=128, double-buffered counted-vmcnt pipeline ----------------
// 512 threads (8 waves, wave-tile 32x64). acc = AhBh + (AhBl + AlBh)/250.
// qk tiles -> qkf f32 ; v tiles -> vb bf16
__global__ __launch_bounds__(512, 2) void k_gemmA(const char* __restrict__ Ai8,
                                                  const char* __restrict__ Wi8,
                                                  const float* __restrict__ biasA,
                                                  float* __restrict__ qkf,
                                                  unsigned short* __restrict__ vb, int Mtiles) {
    __shared__ __align__(16) char Ls[2][4][128 * 128];  // [buf][Ah,Al,Bh,Bl][row*128B]
    int nwg = Mtiles * 13;
    int p = blockIdx.x;
    int xcd = p & 7, o8 = p >> 3;
    int q8_ = nwg >> 3, r8 = nwg & 7;
    int t = (xcd < r8 ? xcd * (q8_ + 1) : r8 * (q8_ + 1) + (xcd - r8) * q8_) + o8;
    int mt = t / 13, nt = t - mt * 13;
    long m0 = (long)mt * 128;
    int n0 = nt * 128;
    int tid = threadIdx.x, lane = tid & 63, wv = tid >> 6;
    int wm = wv >> 1, wn = wv & 1;   // 4 x 2 waves, wave-tile 32(M) x 64(N)

    i32x4 accM[2][4], accC[2][4];
#pragma unroll
    for (int i = 0; i < 2; ++i)
#pragma unroll
        for (int j = 0; j < 4; ++j) { accM[i][j] = (i32x4){0, 0, 0, 0}; accC[i][j] = (i32x4){0, 0, 0, 0}; }

    // Stage one K-tile (64KB) into Ls[BUF]: thread covers 2 rows-of-16B; 8 gll per thread.
    // LDS[row][u] holds global unit (u ^ (row&7)) -> read with the same XOR (proven involution).
#define STAGE(KT, BUF)                                                                           \
    {                                                                                            \
        int kof = (KT) * 128;                                                                    \
        _Pragma("unroll") for (int i = 0; i < 2; ++i) {                                          \
            int row = i * 64 + (tid >> 3);                                                       \
            int gu = (((tid & 7) ^ (row & 7)) << 4);                                             \
            long ao = ((m0 + row) << 10) + kof + gu;                                             \
            long bo = ((long)(n0 + row) << 10) + kof + gu;                                       \
            int dof = i * 8192 + tid * 16;                                                       \
            __builtin_amdgcn_global_load_lds((GVoid*)(Ai8 + ao), (LVoid*)(&Ls[BUF][0][0] + dof), 16, 0, 0); \
            __builtin_amdgcn_global_load_lds((GVoid*)(Ai8 + ao + 512), (LVoid*)(&Ls[BUF][1][0] + dof), 16, 0, 0); \
            __builtin_amdgcn_global_load_lds((GVoid*)(Wi8 + bo), (LVoid*)(&Ls[BUF][2][0] + dof), 16, 0, 0); \
            __builtin_amdgcn_global_load_lds((GVoid*)(Wi8 + bo + 512), (LVoid*)(&Ls[BUF][3][0] + dof), 16, 0, 0); \
        }                                                                                        \
    }

    STAGE(0, 0);
    int cur = 0;
    for (int kt = 0; kt < 4; ++kt) {
        if (kt < 3) {
            if (cur == 0) STAGE(kt + 1, 1) else STAGE(kt + 1, 0);
            asm volatile("s_waitcnt vmcnt(8)" ::: "memory");   // wait kt's loads only; kt+1's stay in flight
        } else {
            asm volatile("s_waitcnt vmcnt(0)" ::: "memory");
        }
        __builtin_amdgcn_s_barrier();
        __builtin_amdgcn_sched_barrier(0);

        const char* Ah = &Ls[cur][0][0];
        const char* Al = &Ls[cur][1][0];
        const char* Bh = &Ls[cur][2][0];
        const char* Bl = &Ls[cur][3][0];
#pragma unroll
        for (int kk = 0; kk < 2; ++kk) {
            i32x4 ah[2], al[2], bh[4], bl[4];
            int kb = kk * 64 + ((lane >> 4) << 4);
#pragma unroll
            for (int mf = 0; mf < 2; ++mf) {
                int row = wm * 32 + mf * 16 + (lane & 15);
                int off = row * 128 + (kb ^ ((row & 7) << 4));
                ah[mf] = *(const i32x4*)(Ah + off);
                al[mf] = *(const i32x4*)(Al + off);
            }
#pragma unroll
            for (int nf = 0; nf < 4; ++nf) {
                int row = wn * 64 + nf * 16 + (lane & 15);
                int off = row * 128 + (kb ^ ((row & 7) << 4));
                bh[nf] = *(const i32x4*)(Bh + off);
                bl[nf] = *(const i32x4*)(Bl + off);
            }
#pragma unroll
            for (int mf = 0; mf < 2; ++mf)
#pragma unroll
                for (int nf = 0; nf < 4; ++nf) {
                    accM[mf][nf] = __builtin_amdgcn_mfma_i32_16x16x64_i8(ah[mf], bh[nf], accM[mf][nf], 0, 0, 0);
                    accC[mf][nf] = __builtin_amdgcn_mfma_i32_16x16x64_i8(ah[mf], bl[nf], accC[mf][nf], 0, 0, 0);
                    accC[mf][nf] = __builtin_amdgcn_mfma_i32_16x16x64_i8(al[mf], bh[nf], accC[mf][nf], 0, 0, 0);
                }
        }
        __builtin_amdgcn_sched_barrier(0);
        __builtin_amdgcn_s_barrier();   // all waves done reading Ls[cur] before it is restaged
        cur ^= 1;
    }
#undef STAGE

#pragma unroll
    for (int nf = 0; nf < 4; ++nf) {
        int n = n0 + wn * 64 + nf * 16 + (lane & 15);
        float scale = (n < 1024) ? SC_QK : (n < 1152 ? SC_CP : SC_QK);
        float bb = biasA[n];
#pragma unroll
        for (int mf = 0; mf < 2; ++mf) {
            long mg = m0 + wm * 32 + mf * 16 + ((lane >> 4) << 2);
#pragma unroll
            for (int r = 0; r < 4; ++r) {
                float val = ((float)accM[mf][nf][r] + CORR * (float)accC[mf][nf][r]) * scale + bb;
                if (n < 1080) qkf[(mg + r) * 1152 + n] = val;
                else if (n >= 1152) vb[(mg + r) * 512 + (n - 1152)] = f2b(val);
            }
        }
    }
}

// ---------------- attention: one b per 512-thread block (proven) ----------------
// qkf row (b,w): [0..511]=q, [512..1023]=k, [1024..1079]=cp cols (h*14+i)
__global__ __launch_bounds__(512) void k_attn(const float* __restrict__ qkf,
                                              const unsigned short* __restrict__ vb,
                                              float* __restrict__ out, int b0) {
    __shared__ float qs[14 * 512];   // row w: 128 16B-units, unit idx ^ (w&7)
    __shared__ float ks[14 * 512];
    __shared__ float cps[56 * 16];   // [h*14+i][j]
    __shared__ float sl[56 * 16];
    __shared__ unsigned short vs[14 * 512];
    int tid = threadIdx.x;
    long mb = (long)blockIdx.x * 14;
    const float4* qk4 = (const float4*)qkf;  // 288 units per row
#pragma unroll
    for (int it = 0; it < 7; ++it) {
        int idx = tid + it * 512;
        int w = idx >> 8, c4 = idx & 255;
        float4 v = qk4[(mb + w) * 288 + c4];
        if (c4 < 128) *(float4*)&qs[w * 512 + ((c4 ^ (w & 7)) << 2)] = v;
        else {
            int uu = c4 - 128;
            *(float4*)&ks[w * 512 + ((uu ^ (w & 7)) << 2)] = v;
        }
    }
#pragma unroll
    for (int it = 0; it < 2; ++it) {
        int idx = tid + it * 512;
        if (idx < 784) {
            int w = idx / 56, tt = idx - w * 56;
            cps[tt * 16 + w] = qkf[(mb + w) * 1152 + 1024 + tt];
        }
    }
#pragma unroll
    for (int it = 0; it < 2; ++it) {
        int idx = tid + it * 512;
        if (idx < 896) {
            int w = idx >> 6, uu = idx & 63;
            *(uint4*)&vs[w * 512 + uu * 8] = *(const uint4*)&vb[(mb + w) * 512 + uu * 8];
        }
    }
    __syncthreads();
    if (tid < 196) {
        int h = tid / 49, r = tid - h * 49;
        int i0 = (r / 7) * 2, j0 = (r - (r / 7) * 7) * 2;
        float a00 = 0.f, a01 = 0.f, a10 = 0.f, a11 = 0.f;
#pragma unroll
        for (int d4 = 0; d4 < 32; ++d4) {
            int uu = h * 32 + d4;
            float4 qa = *(const float4*)&qs[i0 * 512 + ((uu ^ (i0 & 7)) << 2)];
            float4 qb = *(const float4*)&qs[(i0 + 1) * 512 + ((uu ^ ((i0 + 1) & 7)) << 2)];
            float4 ka = *(const float4*)&ks[j0 * 512 + ((uu ^ (j0 & 7)) << 2)];
            float4 kb = *(const float4*)&ks[(j0 + 1) * 512 + ((uu ^ ((j0 + 1) & 7)) << 2)];
            a00 += qa.x * ka.x + qa.y * ka.y + qa.z * ka.z + qa.w * ka.w;
            a01 += qa.x * kb.x + qa.y * kb.y + qa.z * kb.z + qa.w * kb.w;
            a10 += qb.x * ka.x + qb.y * ka.y + qb.z * ka.z + qb.w * ka.w;
            a11 += qb.x * kb.x + qb.y * kb.y + qb.z * kb.z + qb.w * kb.w;
        }
        int base = (h * 14 + i0) * 16 + j0;
        sl[base] = a00 + cps[base];
        sl[base + 1] = a01 + cps[base + 1];
        sl[base + 16] = a10 + cps[base + 16];
        sl[base + 17] = a11 + cps[base + 17];
    }
    __syncthreads();
    if (tid < 56) {
        float* row = &sl[tid * 16];
        float m = row[0];
#pragma unroll
        for (int j = 1; j < 14; ++j) m = fmaxf(m, row[j]);
        float ex[14]; float sum = 0.f;
#pragma unroll
        for (int j = 0; j < 14; ++j) { ex[j] = __expf(row[j] - m); sum += ex[j]; }
        float inv = 1.f / sum;
#pragma unroll
        for (int j = 0; j < 14; ++j) row[j] = ex[j] * inv;
    }
    __syncthreads();
    int c = tid, h = c >> 7;
    float vr[14];
#pragma unroll
    for (int j = 0; j < 14; ++j) vr[j] = b2f(vs[j * 512 + c]);
    float* orow = out + (((long)(b0 + blockIdx.x) * 512 + c) * 14);
    float ob[14];
#pragma unroll
    for (int i = 0; i < 14; ++i) {
        const float* ar = &sl[(h * 14 + i) * 16];
        float a = 0.f;
#pragma unroll
        for (int j = 0; j < 14; ++j) a += vr[j] * ar[j];
        ob[i] = a;
    }
#pragma unroll
    for (int t2 = 0; t2 < 7; ++t2)
        *(float2*)(orow + t2 * 2) = make_float2(ob[2 * t2], ob[2 * t2 + 1]);
}

extern "C" void kernel_launch(void* const* d_in, const int* in_sizes, int n_in,
                              void* d_out, int out_size, void* d_ws, size_t ws_size,
                              hipStream_t stream) {
    const float* x    = (const float*)d_in[0];
    const float* Wq   = (const float*)d_in[1];
    const float* bq   = (const float*)d_in[2];
    const float* Wk   = (const float*)d_in[3];
    const float* bk   = (const float*)d_in[4];
    const float* Wv   = (const float*)d_in[5];
    const float* bv   = (const float*)d_in[6];
    const float* relw = (const float*)d_in[7];
    float* out = (float*)d_out;
    char* ws = (char*)d_ws;

    char*  Wi8   = ws;                       // 1664*1024 = 1703936
    float* biasA = (float*)(ws + 1703936);   // 1664*4 = 6656
    const long WS_DATA = 1712128;

    // per-b: Ai8 14336 + qkf 64512 + vb 14336 = 93184 B
    long avail = (long)ws_size - WS_DATA;
    long nbmax = avail / 93184;
    long NBc = (nbmax / 128) * 128;
    if (NBc > 8192) NBc = 8192;
    if (NBc < 128) NBc = 128;

    char*           Ai8 = ws + WS_DATA;
    float*          qkf = (float*)(Ai8 + NBc * 14336);
    unsigned short* vbw = (unsigned short*)(qkf + NBc * 16128);

    k_prep<<<1593, 256, 0, stream>>>(Wq, Wk, Wv, bq, bk, bv, relw, Wi8, biasA);

    for (int b0 = 0; b0 < 8192; b0 += (int)NBc) {
        int nb = 8192 - b0; if (nb > NBc) nb = (int)NBc;
        int Mtiles = (nb * 14) / 128;
        k_transpose<<<nb, 256, 0, stream>>>(x, Ai8, b0);
        k_gemmA<<<Mtiles * 13, 512, 0, stream>>>(Ai8, Wi8, biasA, qkf, vbw, Mtiles);
        k_attn<<<nb, 512, 0, stream>>>(qkf, vbw, out, b0);
    }
}